// Round 6
// baseline (227.646 us; speedup 1.0000x reference)
//
#include <hip/hip_runtime.h>

typedef float floatx4 __attribute__((ext_vector_type(4)));

#define BB 32
#define HH 56
#define WW 56
#define CC 256
#define PSTRIP 4
#define WSTRIPS 14                      // 56/4
#define HTILE 4                         // rows per block (4 waves, 1 row each)
#define HTILES 14                       // 56/4
#define BLOCKS_PER_IMG (HTILES * WSTRIPS)  // 196

// R12: hoist tap address geometry out of the pixel loop.
// R11 post-mortem: allocator landed at 72 again -- with the 20KB-LDS pin
// giving a 64-reg budget, it relaxed to 7 waves/SIMD instead of spilling.
// The hidden pressure (after consts moved to LDS) is ADDRESS MATH: every
// tap address was recomputed per pixel as xb+(hh*WW+w2)*CC+c0 with
// runtime-d multiplies -> ~15-20 VGPRs of per-tap 64-bit temporaries kept
// live across the 4x-unrolled pixel loop.
// Fix: tap geometry is pixel-invariant. Hoist per wave:
//   rowm/row0/rowp = xb + (h-d / h / h+d)*WW*CC   (3 base ptrs, 6 regs)
//   cdm/cdp       = -d*CC / +d*CC                 (2 regs)
//   rmv/rpv row-validity bools (wave-uniform), wmv/wpv per pixel (trivial)
// Each tap load = base + delta + c0, per-pixel step is a constant +1024B
// that folds into load immediates. Kills the v_mul_lo chains and their
// live ranges; estimated live set ~52-58 < 64.
// Everything else proven and kept: 20KB LDS pin (8 blocks/CU -> 64-reg
// budget), weights+consts in LDS (0 bank conflicts), 2x4 tap batches,
// XCD pinning, NT stores, wave-uniform predication.
// Tripwires: VGPR_Count <= 64 (65-72 = hoist insufficient -> next: 2-kernel
// d-specialization); FETCH ~50MB / WRITE ~100MB (inflation = spill).
// Predicted: occupancy 29->50-75%, dur 94 -> 45-60us.
__global__ __launch_bounds__(256) void dn_kernel(
    const float* __restrict__ x,
    const float* __restrict__ gk_g,
    const float* __restrict__ gs_g,
    const float* __restrict__ beta,
    const float* __restrict__ beta_o,
    const float* __restrict__ gamma_o,
    const int* __restrict__ sdist,
    float* __restrict__ out)
{
    // 20KB: rows 0-7 gk, 8-15 gsw, 16 beta+BETA_MIN, 17 gamma_o, 18 beta_o,
    // row 19 = occupancy-pinning pad (160/20 = exactly 8 blocks/CU).
    __shared__ float lw[20 * CC];

    const int tid = threadIdx.x;

    // Cooperative stage: 19 rows x 256 floats, dwordx4 per thread-iter.
    for (int idx = tid; idx < 19 * 64; idx += 256) {
        const int r  = idx >> 6;
        const int cq = (idx & 63) << 2;
        floatx4 v;
        if (r < 8) {
            v = *reinterpret_cast<const floatx4*>(gk_g + r * CC + cq);
        } else if (r < 16) {
            const int t   = r - 8;
            const int pos = t + (t >= 4 ? 1 : 0);   // skip center of 3x3
            v = *reinterpret_cast<const floatx4*>(gs_g + pos * CC + cq);
        } else if (r == 16) {
            v = *reinterpret_cast<const floatx4*>(beta + cq);
            v += 1e-6f;                             // fold BETA_MIN here
        } else if (r == 17) {
            v = *reinterpret_cast<const floatx4*>(gamma_o + cq);
        } else {
            v = *reinterpret_cast<const floatx4*>(beta_o + cq);
        }
        *reinterpret_cast<floatx4*>(&lw[r * CC + cq]) = v;
    }

    const int d    = sdist[0];                 // surround_dist (=1)
    const int xcd  = blockIdx.x & 7;
    const int q    = blockIdx.x >> 3;          // 0..783
    const int b    = xcd + ((q / BLOCKS_PER_IMG) << 3);
    const int t0   = q % BLOCKS_PER_IMG;
    const int h    = (t0 / WSTRIPS) * HTILE + (tid >> 6);
    const int w0   = (t0 % WSTRIPS) * PSTRIP;
    const int lane = tid & 63;
    const int c0   = lane << 2;                // own channel quad
    const int cg   = c0 & ~7;                  // group base (8 ch)

    const float* xb   = x + (size_t)b * HH * WW * CC;
    const float* row0 = xb + (size_t)h * WW * CC;
    float*       orow = out + ((size_t)(b * HH + h) * WW) * CC;
    const float* wk   = lw + c0;               // per-lane LDS base

    // Hoisted tap geometry (pixel-invariant).
    const int  hm  = h - d, hp = h + d;
    const bool rmv = (unsigned)hm < HH;        // wave-uniform
    const bool rpv = (unsigned)hp < HH;
    const float* rowm = xb + (long)hm * (WW * CC);   // only deref'd if rmv
    const float* rowp = xb + (long)hp * (WW * CC);   // only deref'd if rpv
    const int cdm = -d * CC;                   // column deltas (floats)
    const int cdp =  d * CC;

    __syncthreads();

    const floatx4 zero = {0.f, 0.f, 0.f, 0.f};

#pragma unroll
    for (int j = 0; j < PSTRIP; ++j) {
        const int w = w0 + j;
        const bool wmv = (w - d) >= 0;
        const bool wpv = (w + d) < WW;
        const float* cp = row0 + w * CC;
        const float* mp = rowm + w * CC;
        const float* pp = rowp + w * CC;

        // center: full 8-ch group (lane pairs duplicate-read the same 32B)
        floatx4 cxa = *reinterpret_cast<const floatx4*>(cp + cg);
        floatx4 cxb = *reinterpret_cast<const floatx4*>(cp + cg + 4);

        // tap batch A: tt0..3 = (top-left, top, top-right, mid-left)
        floatx4 tp[4];
        tp[0] = (rmv && wmv) ? *reinterpret_cast<const floatx4*>(mp + cdm + c0) : zero;
        tp[1] =  rmv         ? *reinterpret_cast<const floatx4*>(mp       + c0) : zero;
        tp[2] = (rmv && wpv) ? *reinterpret_cast<const floatx4*>(mp + cdp + c0) : zero;
        tp[3] =         wmv  ? *reinterpret_cast<const floatx4*>(cp + cdm + c0) : zero;

        // Pk under batch-A latency: 8 group inputs x own 4 outputs
        const floatx4 cxo = (lane & 1) ? cxb : cxa;
        const floatx4 sqa = cxa * cxa, sqb = cxb * cxb;
        floatx4 acc = *reinterpret_cast<const floatx4*>(wk + 16 * CC); // beta
#pragma unroll
        for (int i = 0; i < 4; ++i)
            acc += sqa[i] * *reinterpret_cast<const floatx4*>(wk + i * CC);
#pragma unroll
        for (int i = 0; i < 4; ++i)
            acc += sqb[i] * *reinterpret_cast<const floatx4*>(wk + (4 + i) * CC);

        // consume batch A (gsw rows 8..11)
#pragma unroll
        for (int tt = 0; tt < 4; ++tt)
            acc += (tp[tt] * tp[tt]) *
                   *reinterpret_cast<const floatx4*>(wk + (8 + tt) * CC);

        // tap batch B: tt4..7 = (mid-right, bot-left, bot, bot-right)
        tp[0] =         wpv  ? *reinterpret_cast<const floatx4*>(cp + cdp + c0) : zero;
        tp[1] = (rpv && wmv) ? *reinterpret_cast<const floatx4*>(pp + cdm + c0) : zero;
        tp[2] =  rpv         ? *reinterpret_cast<const floatx4*>(pp       + c0) : zero;
        tp[3] = (rpv && wpv) ? *reinterpret_cast<const floatx4*>(pp + cdp + c0) : zero;

#pragma unroll
        for (int tt = 0; tt < 4; ++tt)
            acc += (tp[tt] * tp[tt]) *
                   *reinterpret_cast<const floatx4*>(wk + (12 + tt) * CC);

        // epilogue: gov/bov from LDS (transient regs)
        const floatx4 gov = *reinterpret_cast<const floatx4*>(wk + 17 * CC);
        const floatx4 bov = *reinterpret_cast<const floatx4*>(wk + 18 * CC);
        floatx4 res;
#pragma unroll
        for (int o = 0; o < 4; ++o)
            res[o] = cxo[o] * __builtin_amdgcn_rsqf(acc[o]) * gov[o] + bov[o];

        __builtin_nontemporal_store(res,
            reinterpret_cast<floatx4*>(orow + w * CC + c0));
    }
}

extern "C" void kernel_launch(void* const* d_in, const int* in_sizes, int n_in,
                              void* d_out, int out_size, void* d_ws, size_t ws_size,
                              hipStream_t stream) {
    const float* x       = (const float*)d_in[0];
    const float* gamma_k = (const float*)d_in[1];
    const float* gamma_s = (const float*)d_in[2];
    const float* beta    = (const float*)d_in[3];
    const float* beta_o  = (const float*)d_in[4];
    const float* gamma_o = (const float*)d_in[5];
    const int*   sdist   = (const int*)d_in[6];
    float* out = (float*)d_out;

    const int blocks = BB * BLOCKS_PER_IMG;   // 6272
    dn_kernel<<<blocks, 256, 0, stream>>>(x, gamma_k, gamma_s, beta,
                                          beta_o, gamma_o, sdist, out);
}